// Round 1
// baseline (87.237 us; speedup 1.0000x reference)
//
#include <hip/hip_runtime.h>
#include <math.h>

#define BB 32
#define CC 5
#define HH 50
#define LL 32
#define LEV 3
#define DD 256
#define KK 10
#define THRESH 0.1f
#define EPSF 1e-12f

// ---------------- Kernel 1: y = l2norm(x @ W + b) for cdd (B*C rows) and his (B*H rows)
// One block per row, 256 threads; thread j computes output column j.
__global__ void proj_norm_kernel(const float* __restrict__ cdd,
                                 const float* __restrict__ his,
                                 const float* __restrict__ W,
                                 const float* __restrict__ bias,
                                 float* __restrict__ c_out,   // [B*C, D]
                                 float* __restrict__ h_out)   // [B*H, D]
{
    const int row = blockIdx.x;          // 0 .. B*C + B*H - 1
    const int j   = threadIdx.x;         // 0..255

    const float* x;
    float* y;
    if (row < BB * CC) {
        x = cdd + (size_t)row * DD;
        y = c_out + (size_t)row * DD;
    } else {
        const int r = row - BB * CC;
        x = his + (size_t)r * DD;
        y = h_out + (size_t)r * DD;
    }

    __shared__ float xs[DD];
    xs[j] = x[j];
    __syncthreads();

    // 4 partial accumulators to break the FMA dependence chain.
    float a0 = 0.f, a1 = 0.f, a2 = 0.f, a3 = 0.f;
    #pragma unroll 4
    for (int d = 0; d < DD; d += 4) {
        a0 += xs[d + 0] * W[(size_t)(d + 0) * DD + j];   // coalesced across j
        a1 += xs[d + 1] * W[(size_t)(d + 1) * DD + j];
        a2 += xs[d + 2] * W[(size_t)(d + 2) * DD + j];
        a3 += xs[d + 3] * W[(size_t)(d + 3) * DD + j];
    }
    float acc = bias[j] + ((a0 + a1) + (a2 + a3));

    // block reduction of sum of squares
    __shared__ float red[DD];
    red[j] = acc * acc;
    __syncthreads();
    for (int s = DD / 2; s > 0; s >>= 1) {
        if (j < s) red[j] += red[j + s];
        __syncthreads();
    }
    const float norm = sqrtf(red[0]);
    const float inv  = 1.0f / fmaxf(norm, EPSF);
    y[j] = acc * inv;
}

// ---------------- Kernel 2: attn[b,c,h] = c_n[b,c,:] . h_n[b,h,:]; then top-K per (b,c)
// One block per (b,c). 4 waves; wave w handles h = w, w+4, ...
__global__ void attn_topk_kernel(const float* __restrict__ c_n,  // [B*C, D]
                                 const float* __restrict__ h_n,  // [B*H, D]
                                 float* __restrict__ w_out,      // [B*C*K] (already masked)
                                 int* __restrict__ idx_out)      // [B*C*K]
{
    const int bc   = blockIdx.x;     // 0..159
    const int b    = bc / CC;
    const int tid  = threadIdx.x;    // 0..255
    const int wid  = tid >> 6;
    const int lane = tid & 63;

    __shared__ float cs[DD];
    __shared__ float attn_s[HH];
    cs[tid] = c_n[(size_t)bc * DD + tid];
    __syncthreads();

    for (int h = wid; h < HH; h += 4) {
        const float* hr = h_n + (size_t)(b * HH + h) * DD;
        float p = 0.f;
        #pragma unroll
        for (int i = 0; i < 4; ++i) {
            const int d = lane + i * 64;
            p += cs[d] * hr[d];
        }
        // wave-64 butterfly reduce
        #pragma unroll
        for (int off = 32; off > 0; off >>= 1)
            p += __shfl_down(p, off, 64);
        if (lane == 0) attn_s[h] = p;
    }
    __syncthreads();

    if (tid == 0) {
        // stable descending selection: largest value, ties -> lowest index
        unsigned long long usedm = 0ull;
        for (int k = 0; k < KK; ++k) {
            float best = -INFINITY;
            int bi = 0;
            for (int h = 0; h < HH; ++h) {
                if (!((usedm >> h) & 1ull) && attn_s[h] > best) {
                    best = attn_s[h];
                    bi = h;
                }
            }
            usedm |= (1ull << bi);
            w_out[bc * KK + k]   = (best < THRESH) ? 0.0f : best;
            idx_out[bc * KK + k] = bi;
        }
    }
}

// ---------------- Kernel 3: out[b,c,k,:,:,:] = emb[b, idx[b,c,k], :,:,:] * w[b,c,k]
// One block per (b,c,k); 24576 floats = 6144 float4 per block.
__global__ void gather_scale_kernel(const float* __restrict__ emb,  // [B,H, L*LEV*D]
                                    const float* __restrict__ w,
                                    const int* __restrict__ idx,
                                    float* __restrict__ out)
{
    const int INNER  = LL * LEV * DD;   // 24576
    const int INNER4 = INNER / 4;       // 6144
    const int blk = blockIdx.x;         // 0 .. B*C*K-1
    const int b   = blk / (CC * KK);

    const float wv = w[blk];
    const int hi   = idx[blk];

    float4* dst = (float4*)(out + (size_t)blk * INNER);

    if (wv == 0.0f) {
        const float4 z = make_float4(0.f, 0.f, 0.f, 0.f);
        for (int i = threadIdx.x; i < INNER4; i += blockDim.x)
            dst[i] = z;
    } else {
        const float4* src = (const float4*)(emb + ((size_t)(b * HH + hi)) * INNER);
        for (int i = threadIdx.x; i < INNER4; i += blockDim.x) {
            float4 v = src[i];
            dst[i] = make_float4(v.x * wv, v.y * wv, v.z * wv, v.w * wv);
        }
    }
}

extern "C" void kernel_launch(void* const* d_in, const int* in_sizes, int n_in,
                              void* d_out, int out_size, void* d_ws, size_t ws_size,
                              hipStream_t stream) {
    const float* cdd  = (const float*)d_in[0];   // [B,C,D]
    const float* his  = (const float*)d_in[1];   // [B,H,D]
    const float* emb  = (const float*)d_in[2];   // [B,H,L,LEV,D]
    const float* W    = (const float*)d_in[3];   // [D,D]
    const float* bias = (const float*)d_in[4];   // [D]
    float* out = (float*)d_out;

    // workspace layout
    char* ws = (char*)d_ws;
    float* c_n  = (float*)ws;                                   // B*C*D floats   = 163840 B
    float* h_n  = (float*)(ws + 163840);                        // B*H*D floats   = 1638400 B
    float* wv   = (float*)(ws + 163840 + 1638400);              // B*C*K floats   = 6400 B
    int*   idx  = (int*)  (ws + 163840 + 1638400 + 6400);       // B*C*K ints     = 6400 B

    proj_norm_kernel<<<BB * CC + BB * HH, DD, 0, stream>>>(cdd, his, W, bias, c_n, h_n);
    attn_topk_kernel<<<BB * CC, DD, 0, stream>>>(c_n, h_n, wv, idx);
    gather_scale_kernel<<<BB * CC * KK, 256, 0, stream>>>(emb, wv, idx, out);
}

// Round 3
// 78.288 us; speedup vs baseline: 1.1143x; 1.1143x over previous
//
#include <hip/hip_runtime.h>
#include <math.h>

#define BB 32
#define CC 5
#define HH 50
#define LL 32
#define LEV 3
#define DD 256
#define KK 10
#define THRESH 0.1f
#define EPSF 1e-12f
#define RPB 8                      // rows per block in proj kernel
#define NROWS (BB * CC + BB * HH)  // 1760, divisible by RPB

typedef float f32x4 __attribute__((ext_vector_type(4)));

// ---------------- Kernel 1: y = l2norm(x @ W + b), 8 rows per block.
// Thread j computes column j for all 8 rows; W row is loaded once per block
// (L2 traffic /8 vs one-row-per-block).
__global__ void proj_norm_kernel(const float* __restrict__ cdd,
                                 const float* __restrict__ his,
                                 const float* __restrict__ W,
                                 const float* __restrict__ bias,
                                 float* __restrict__ c_out,   // [B*C, D]
                                 float* __restrict__ h_out)   // [B*H, D]
{
    const int row0 = blockIdx.x * RPB;
    const int j    = threadIdx.x;     // 0..255
    const int wid  = j >> 6;
    const int lane = j & 63;

    __shared__ float xs[RPB][DD];
    #pragma unroll
    for (int r = 0; r < RPB; ++r) {
        const int row = row0 + r;
        const float* x = (row < BB * CC) ? (cdd + (size_t)row * DD)
                                         : (his + (size_t)(row - BB * CC) * DD);
        xs[r][j] = x[j];
    }
    __syncthreads();

    const float bj = bias[j];
    float acc[RPB];
    #pragma unroll
    for (int r = 0; r < RPB; ++r) acc[r] = bj;

    for (int d = 0; d < DD; d += 4) {
        const float w0 = W[(size_t)(d + 0) * DD + j];   // coalesced across j, L2-hit
        const float w1 = W[(size_t)(d + 1) * DD + j];
        const float w2 = W[(size_t)(d + 2) * DD + j];
        const float w3 = W[(size_t)(d + 3) * DD + j];
        #pragma unroll
        for (int r = 0; r < RPB; ++r) {
            const float4 xv = *(const float4*)&xs[r][d];   // ds_read_b128, broadcast
            acc[r] = fmaf(xv.x, w0, fmaf(xv.y, w1, fmaf(xv.z, w2, fmaf(xv.w, w3, acc[r]))));
        }
    }

    // per-row sum of squares: wave shuffle reduce, then 4 partials via LDS
    __shared__ float part[RPB][4];
    #pragma unroll
    for (int r = 0; r < RPB; ++r) {
        float s = acc[r] * acc[r];
        #pragma unroll
        for (int off = 32; off > 0; off >>= 1) s += __shfl_xor(s, off, 64);
        if (lane == 0) part[r][wid] = s;
    }
    __syncthreads();
    __shared__ float inv_s[RPB];
    if (j < RPB) {
        const float s = part[j][0] + part[j][1] + part[j][2] + part[j][3];
        inv_s[j] = 1.0f / fmaxf(sqrtf(s), EPSF);
    }
    __syncthreads();

    #pragma unroll
    for (int r = 0; r < RPB; ++r) {
        const int row = row0 + r;
        float* y = (row < BB * CC) ? (c_out + (size_t)row * DD)
                                   : (h_out + (size_t)(row - BB * CC) * DD);
        y[j] = acc[r] * inv_s[r];
    }
}

// ---------------- Kernel 2: attn + wave-parallel top-K per (b,c).
__global__ void attn_topk_kernel(const float* __restrict__ c_n,  // [B*C, D]
                                 const float* __restrict__ h_n,  // [B*H, D]
                                 float* __restrict__ w_out,      // [B*C*K] (masked)
                                 int* __restrict__ idx_out)      // [B*C*K]
{
    const int bc   = blockIdx.x;     // 0..159
    const int b    = bc / CC;
    const int tid  = threadIdx.x;    // 0..255
    const int wid  = tid >> 6;
    const int lane = tid & 63;

    __shared__ float cs[DD];
    __shared__ float attn_s[64];
    cs[tid] = c_n[(size_t)bc * DD + tid];
    if (tid < 64) attn_s[tid] = -INFINITY;
    __syncthreads();

    for (int h = wid; h < HH; h += 4) {
        const float* hr = h_n + (size_t)(b * HH + h) * DD;
        float p = 0.f;
        #pragma unroll
        for (int i = 0; i < 4; ++i) p += cs[lane + i * 64] * hr[lane + i * 64];
        #pragma unroll
        for (int off = 32; off > 0; off >>= 1) p += __shfl_down(p, off, 64);
        if (lane == 0) attn_s[h] = p;
    }
    __syncthreads();

    // wave 0: 10 rounds of butterfly argmax (tie -> lowest index, = lax.top_k)
    if (wid == 0) {
        float v   = attn_s[lane];    // lanes 50..63 hold -inf
        int   myi = lane;
        for (int k = 0; k < KK; ++k) {
            float bv = v;
            int   bi = myi;
            #pragma unroll
            for (int off = 32; off > 0; off >>= 1) {
                const float ov = __shfl_xor(bv, off, 64);
                const int   oi = __shfl_xor(bi, off, 64);
                if (ov > bv || (ov == bv && oi < bi)) { bv = ov; bi = oi; }
            }
            if (lane == 0) {
                w_out[bc * KK + k]   = (bv < THRESH) ? 0.0f : bv;
                idx_out[bc * KK + k] = bi;
            }
            if (myi == bi) v = -INFINITY;   // remove winner
        }
    }
}

// ---------------- Kernel 3: out[b,c,k,:] = emb[b, idx[b,c,k], :] * w[b,c,k]
// 4 chunk-blocks per (b,c,k) for load balance; nontemporal stores.
#define CHUNKS 4
__global__ void gather_scale_kernel(const float* __restrict__ emb,  // [B,H, L*LEV*D]
                                    const float* __restrict__ w,
                                    const int* __restrict__ idx,
                                    float* __restrict__ out)
{
    const int INNER  = LL * LEV * DD;       // 24576
    const int INNER4 = INNER / 4;           // 6144
    const int PER    = INNER4 / CHUNKS;     // 1536 float4 per chunk-block

    const int g     = blockIdx.x;
    const int blk   = g / CHUNKS;           // (b,c,k)
    const int chunk = g % CHUNKS;
    const int b     = blk / (CC * KK);

    const float wv = w[blk];
    const int   hi = idx[blk];

    f32x4* dst = (f32x4*)(out + (size_t)blk * INNER) + (size_t)chunk * PER;

    if (wv == 0.0f) {
        const f32x4 z = (f32x4){0.f, 0.f, 0.f, 0.f};
        for (int i = threadIdx.x; i < PER; i += 256)
            __builtin_nontemporal_store(z, &dst[i]);
    } else {
        const f32x4* src = (const f32x4*)(emb + (size_t)(b * HH + hi) * INNER)
                           + (size_t)chunk * PER;
        for (int i = threadIdx.x; i < PER; i += 256) {
            const f32x4 v = src[i];
            __builtin_nontemporal_store(v * wv, &dst[i]);
        }
    }
}

extern "C" void kernel_launch(void* const* d_in, const int* in_sizes, int n_in,
                              void* d_out, int out_size, void* d_ws, size_t ws_size,
                              hipStream_t stream) {
    const float* cdd  = (const float*)d_in[0];   // [B,C,D]
    const float* his  = (const float*)d_in[1];   // [B,H,D]
    const float* emb  = (const float*)d_in[2];   // [B,H,L,LEV,D]
    const float* W    = (const float*)d_in[3];   // [D,D]
    const float* bias = (const float*)d_in[4];   // [D]
    float* out = (float*)d_out;

    // workspace layout
    char* ws = (char*)d_ws;
    float* c_n = (float*)ws;                               // B*C*D floats = 163840 B
    float* h_n = (float*)(ws + 163840);                    // B*H*D floats = 1638400 B
    float* wv  = (float*)(ws + 163840 + 1638400);          // B*C*K floats = 6400 B
    int*   idx = (int*)  (ws + 163840 + 1638400 + 6400);   // B*C*K ints   = 6400 B

    proj_norm_kernel<<<NROWS / RPB, DD, 0, stream>>>(cdd, his, W, bias, c_n, h_n);
    attn_topk_kernel<<<BB * CC, DD, 0, stream>>>(c_n, h_n, wv, idx);
    gather_scale_kernel<<<BB * CC * KK * CHUNKS, 256, 0, stream>>>(emb, wv, idx, out);
}